// Round 2
// baseline (11779.964 us; speedup 1.0000x reference)
//
#include <hip/hip_runtime.h>
#include <stdint.h>

// Bidirectional LSTM.  B=32, T=512, V=32000, D=300, U=300, NT=3.
// Float-tensor dtype (f32 vs bf16) is detected at runtime from the bit
// patterns of `emb`; internals are canonicalized to bf16 in d_ws, compute f32.

#define BB 32
#define TT 512
#define DD 300
#define UU 300
#define G4 1200   // 4*U
#define NTOK 3

typedef uint16_t bf16_t;

__device__ __forceinline__ float bf2f(uint16_t u) {
    union { uint32_t i; float f; } v; v.i = ((uint32_t)u) << 16; return v.f;
}
__device__ __forceinline__ uint16_t f2bf(float f) {
    union { uint32_t i; float f; } v; v.f = f;
    uint32_t r = v.i + 0x7fffu + ((v.i >> 16) & 1u);   // RNE
    return (uint16_t)(r >> 16);
}
// load float input element idx from base, interpreting per flag
__device__ __forceinline__ float ldf(const void* base, size_t idx, int f32m) {
    return f32m ? ((const float*)base)[idx]
                : bf2f(((const uint16_t*)base)[idx]);
}

// ---------------------------------------------------------------------------
// Kernel 0: dtype detector. If emb holds packed f32, the even u16 halves are
// f32 mantissa low-bits -> random exponents when read as bf16 -> huge values.
// If emb is real bf16, every even element is ~N(0, 0.05).
// ---------------------------------------------------------------------------
__global__ void detect_dtype(const uint16_t* __restrict__ emb_u16,
                             int* __restrict__ flag) {
    __shared__ float red[256];
    const int tid = threadIdx.x;
    float m = 0.f;
    for (int k = tid; k < 4096; k += 256)
        m = fmaxf(m, fabsf(bf2f(emb_u16[2 * k])));
    red[tid] = m;
    __syncthreads();
    for (int s = 128; s > 0; s >>= 1) {
        if (tid < s) red[tid] = fmaxf(red[tid], red[tid + s]);
        __syncthreads();
    }
    if (tid == 0) flag[0] = (red[0] > 1.0e3f) ? 1 : 0;   // 1 = f32 inputs
}

// ---------------------------------------------------------------------------
// Kernel 1: transpose Wr (300 x 1200) -> WrT (1200 x 304, zero padded), bf16.
// ---------------------------------------------------------------------------
__global__ void prep_wrt(const void* __restrict__ Wr_f,
                         const void* __restrict__ Wr_b,
                         bf16_t* __restrict__ WrT_f,
                         bf16_t* __restrict__ WrT_b,
                         const int* __restrict__ flagp) {
    const int f32m = *flagp;
    int idx = blockIdx.x * 256 + threadIdx.x;          // over 1200*304
    const void* src = blockIdx.y ? Wr_b : Wr_f;
    bf16_t*     dst = blockIdx.y ? WrT_b : WrT_f;
    if (idx < G4 * 304) {
        int j = idx / 304;
        int u = idx - j * 304;
        float v = (u < UU) ? ldf(src, (size_t)u * G4 + j, f32m) : 0.f;
        dst[idx] = f2bf(v);
    }
}

// ---------------------------------------------------------------------------
// Kernel 2: zx[r][j] = sum_d emb[inputs[r]][d] * Wk[d][j] + b[j]  (bf16 out)
// ---------------------------------------------------------------------------
#define BM 64
#define BN 64
#define BK 16
__global__ __launch_bounds__(256) void zx_gemm(
    const int* __restrict__ inputs, const void* __restrict__ emb,
    const void* __restrict__ Wk_f, const void* __restrict__ b_f,
    const void* __restrict__ Wk_b, const void* __restrict__ b_b,
    bf16_t* __restrict__ zxf, bf16_t* __restrict__ zxb,
    const int* __restrict__ flagp) {

    const int f32m = *flagp;
    const int dir = blockIdx.z;
    const void* Wk   = dir ? Wk_b : Wk_f;
    const void* bias = dir ? b_b  : b_f;
    bf16_t*     out  = dir ? zxb  : zxf;

    __shared__ __align__(16) float As[BM][BK + 1];
    __shared__ __align__(16) float Bs[BK][BN];
    __shared__ int rowids[BM];

    const int tid = threadIdx.x;
    const int rowBase = blockIdx.y * BM;
    const int colBase = blockIdx.x * BN;

    if (tid < BM) rowids[tid] = inputs[rowBase + tid];
    __syncthreads();

    float acc[4][4] = {};
    const int tx = tid & 15;       // col group
    const int ty = tid >> 4;       // row group

    for (int k0 = 0; k0 < DD; k0 += BK) {
#pragma unroll
        for (int i = 0; i < 4; i++) {
            int idx = tid + i * 256;
            int r = idx >> 4, k = idx & 15;
            int kk = k0 + k;
            float v = 0.f;
            if (kk < DD) v = ldf(emb, (size_t)rowids[r] * DD + kk, f32m);
            As[r][k] = v;
        }
#pragma unroll
        for (int i = 0; i < 4; i++) {
            int idx = tid + i * 256;
            int k = idx >> 6, c = idx & 63;
            int kk = k0 + k;
            int col = colBase + c;
            float v = 0.f;
            if (kk < DD && col < G4) v = ldf(Wk, (size_t)kk * G4 + col, f32m);
            Bs[k][c] = v;
        }
        __syncthreads();
#pragma unroll
        for (int k = 0; k < BK; k++) {
            float a0 = As[ty * 4 + 0][k];
            float a1 = As[ty * 4 + 1][k];
            float a2 = As[ty * 4 + 2][k];
            float a3 = As[ty * 4 + 3][k];
            float4 b4 = *(const float4*)&Bs[k][tx * 4];
            acc[0][0] += a0 * b4.x; acc[0][1] += a0 * b4.y; acc[0][2] += a0 * b4.z; acc[0][3] += a0 * b4.w;
            acc[1][0] += a1 * b4.x; acc[1][1] += a1 * b4.y; acc[1][2] += a1 * b4.z; acc[1][3] += a1 * b4.w;
            acc[2][0] += a2 * b4.x; acc[2][1] += a2 * b4.y; acc[2][2] += a2 * b4.z; acc[2][3] += a2 * b4.w;
            acc[3][0] += a3 * b4.x; acc[3][1] += a3 * b4.y; acc[3][2] += a3 * b4.z; acc[3][3] += a3 * b4.w;
        }
        __syncthreads();
    }

#pragma unroll
    for (int i = 0; i < 4; i++) {
        int r = rowBase + ty * 4 + i;
#pragma unroll
        for (int jj = 0; jj < 4; jj++) {
            int col = colBase + tx * 4 + jj;
            if (col < G4)
                out[(size_t)r * G4 + col] = f2bf(acc[i][jj] + ldf(bias, col, f32m));
        }
    }
}

// ---------------------------------------------------------------------------
// Kernel 3: LSTM recurrence. One block per (batch, direction). 256 threads.
// ---------------------------------------------------------------------------
__device__ __forceinline__ float dot8(uint4 q, float4 ha, float4 hb) {
    union { uint32_t i; float f; } t;
    float s;
    t.i = q.x << 16;          s  = t.f * ha.x;
    t.i = q.x & 0xffff0000u;  s += t.f * ha.y;
    t.i = q.y << 16;          s += t.f * ha.z;
    t.i = q.y & 0xffff0000u;  s += t.f * ha.w;
    t.i = q.z << 16;          s += t.f * hb.x;
    t.i = q.z & 0xffff0000u;  s += t.f * hb.y;
    t.i = q.w << 16;          s += t.f * hb.z;
    t.i = q.w & 0xffff0000u;  s += t.f * hb.w;
    return s;
}

__global__ __launch_bounds__(256) void lstm_rec(
    const bf16_t* __restrict__ zxf, const bf16_t* __restrict__ zxb,
    const bf16_t* __restrict__ WrT_f, const bf16_t* __restrict__ WrT_b,
    const int* __restrict__ seqlen,
    bf16_t* __restrict__ hf, bf16_t* __restrict__ hb) {

    const int b   = blockIdx.x;   // 0..31
    const int dir = blockIdx.y;   // 0 = fwd, 1 = bwd
    const bf16_t* zx  = dir ? zxb   : zxf;
    const bf16_t* WrT = dir ? WrT_b : WrT_f;
    bf16_t*       hout = dir ? hb : hf;
    const int L = seqlen[b];

    __shared__ __align__(16) float h_s[304];
    __shared__ __align__(16) float c_s[304];
    __shared__ __align__(16) float z_s[G4];

    const int tid = threadIdx.x;
    for (int i = tid; i < 304; i += 256) { h_s[i] = 0.f; c_s[i] = 0.f; }
    __syncthreads();

    const size_t zbase = (size_t)b * TT * G4;
    const int j0 = tid, j1 = tid + 256, j2 = tid + 512, j3 = tid + 768, j4 = tid + 1024;
    const bool v4 = (j4 < G4);
    const int j4c = v4 ? j4 : 0;
    const bf16_t* w0 = WrT + (size_t)j0 * 304;
    const bf16_t* w1 = WrT + (size_t)j1 * 304;
    const bf16_t* w2 = WrT + (size_t)j2 * 304;
    const bf16_t* w3 = WrT + (size_t)j3 * 304;
    const bf16_t* w4 = WrT + (size_t)j4c * 304;

    for (int step = 0; step < TT; step++) {
        const int t = dir ? (TT - 1 - step) : step;
        const bf16_t* zrow = zx + zbase + (size_t)t * G4;

        float a0 = 0.f, a1 = 0.f, a2 = 0.f, a3 = 0.f, a4 = 0.f;
#pragma unroll 4
        for (int u0 = 0; u0 < 304; u0 += 8) {
            const float4* hp = (const float4*)&h_s[u0];
            float4 ha = hp[0], hbv = hp[1];
            uint4 q0 = *(const uint4*)(w0 + u0);
            uint4 q1 = *(const uint4*)(w1 + u0);
            uint4 q2 = *(const uint4*)(w2 + u0);
            uint4 q3 = *(const uint4*)(w3 + u0);
            uint4 q4 = *(const uint4*)(w4 + u0);
            a0 += dot8(q0, ha, hbv);
            a1 += dot8(q1, ha, hbv);
            a2 += dot8(q2, ha, hbv);
            a3 += dot8(q3, ha, hbv);
            a4 += dot8(q4, ha, hbv);
        }
        z_s[j0] = a0 + bf2f(zrow[j0]);
        z_s[j1] = a1 + bf2f(zrow[j1]);
        z_s[j2] = a2 + bf2f(zrow[j2]);
        z_s[j3] = a3 + bf2f(zrow[j3]);
        if (v4) z_s[j4] = a4 + bf2f(zrow[j4]);
        __syncthreads();

        for (int u = tid; u < UU; u += 256) {
            float zi = z_s[u];
            float zf = z_s[u + UU];
            float zg = z_s[u + 2 * UU];
            float zo = z_s[u + 3 * UU];
            float si = 1.f / (1.f + __expf(-zi));
            float sf = 1.f / (1.f + __expf(-zf));
            float so = 1.f / (1.f + __expf(-zo));
            float tg = tanhf(zg);
            float cn = sf * c_s[u] + si * tg;
            float hn = so * tanhf(cn);
            if (t < L) { h_s[u] = hn; c_s[u] = cn; }
            hout[((size_t)b * TT + t) * UU + u] = f2bf(h_s[u]);
        }
        __syncthreads();
    }
}

// ---------------------------------------------------------------------------
// Kernel 4: out[r][n] = [hf[r] ; hb[r]] @ fc_W + fc_b.  One thread per r.
// ---------------------------------------------------------------------------
__global__ __launch_bounds__(256) void fc_out(
    const bf16_t* __restrict__ hf, const bf16_t* __restrict__ hb,
    const void* __restrict__ fcW, const void* __restrict__ fcb,
    void* __restrict__ out, const int* __restrict__ flagp) {

    const int f32m = *flagp;
    __shared__ float W[2 * UU * NTOK];
    __shared__ float bias[NTOK];
    const int tid = threadIdx.x;
    for (int i = tid; i < 2 * UU * NTOK; i += 256) W[i] = ldf(fcW, i, f32m);
    if (tid < NTOK) bias[tid] = ldf(fcb, tid, f32m);
    __syncthreads();

    const int r = blockIdx.x * 256 + tid;   // < 16384
    const bf16_t* hfr = hf + (size_t)r * UU;
    const bf16_t* hbr = hb + (size_t)r * UU;
    float s0 = bias[0], s1 = bias[1], s2 = bias[2];
    for (int u = 0; u < UU; u++) {
        float f = bf2f(hfr[u]);
        s0 += f * W[u * 3 + 0];
        s1 += f * W[u * 3 + 1];
        s2 += f * W[u * 3 + 2];
    }
    for (int u = 0; u < UU; u++) {
        float f = bf2f(hbr[u]);
        s0 += f * W[(UU + u) * 3 + 0];
        s1 += f * W[(UU + u) * 3 + 1];
        s2 += f * W[(UU + u) * 3 + 2];
    }
    if (f32m) {
        float* o = (float*)out;
        o[(size_t)r * 3 + 0] = s0;
        o[(size_t)r * 3 + 1] = s1;
        o[(size_t)r * 3 + 2] = s2;
    } else {
        bf16_t* o = (bf16_t*)out;
        o[(size_t)r * 3 + 0] = f2bf(s0);
        o[(size_t)r * 3 + 1] = f2bf(s1);
        o[(size_t)r * 3 + 2] = f2bf(s2);
    }
}

// ---------------------------------------------------------------------------
extern "C" void kernel_launch(void* const* d_in, const int* in_sizes, int n_in,
                              void* d_out, int out_size, void* d_ws, size_t ws_size,
                              hipStream_t stream) {
    const int* inputs = (const int*)d_in[0];
    const int* seqlen = (const int*)d_in[1];
    const void* emb  = d_in[2];
    const void* Wk_f = d_in[3];
    const void* Wr_f = d_in[4];
    const void* b_f  = d_in[5];
    const void* Wk_b = d_in[6];
    const void* Wr_b = d_in[7];
    const void* b_b  = d_in[8];
    const void* fcW  = d_in[9];
    const void* fcb  = d_in[10];

    // workspace layout (bytes), 16B aligned
    char* ws = (char*)d_ws;
    int*    flag  = (int*)(ws + 0);                 // 64 B reserved
    bf16_t* WrT_f = (bf16_t*)(ws + 64);             // 729600
    bf16_t* WrT_b = (bf16_t*)(ws + 729664);         // 729600
    bf16_t* zxf   = (bf16_t*)(ws + 1459264);        // 39321600
    bf16_t* zxb   = (bf16_t*)(ws + 40780864);       // 39321600
    bf16_t* hfbuf = (bf16_t*)(ws + 80102464);       // 9830400
    bf16_t* hbbuf = (bf16_t*)(ws + 89932864);       // 9830400 -> total 99763264

    detect_dtype<<<1, 256, 0, stream>>>((const uint16_t*)emb, flag);
    {
        dim3 grid((G4 * 304 + 255) / 256, 2);
        prep_wrt<<<grid, 256, 0, stream>>>(Wr_f, Wr_b, WrT_f, WrT_b, flag);
    }
    {
        dim3 grid((G4 + BN - 1) / BN, (BB * TT) / BM, 2);   // 19 x 256 x 2
        zx_gemm<<<grid, 256, 0, stream>>>(inputs, emb, Wk_f, b_f, Wk_b, b_b,
                                          zxf, zxb, flag);
    }
    {
        dim3 grid(BB, 2);
        lstm_rec<<<grid, 256, 0, stream>>>(zxf, zxb, WrT_f, WrT_b, seqlen,
                                           hfbuf, hbbuf);
    }
    fc_out<<<(BB * TT) / 256, 256, 0, stream>>>(hfbuf, hbbuf, fcW, fcb,
                                                d_out, flag);
}

// Round 4
// 5418.109 us; speedup vs baseline: 2.1742x; 2.1742x over previous
//
#include <hip/hip_runtime.h>
#include <stdint.h>

// Bidirectional LSTM.  B=32, T=512, V=32000, D=300, U=300, NT=3.
// R4: R3 structure with the NaN fix — Hlds K-pad region (elems 304..327 per
// row) was uninitialized LDS read by the kt=9 MFMA A-fragment (NaN*0=NaN).
// Now zeroed once; per-step loads only touch [0,304).

#define BB 32
#define TT 512
#define DD 300
#define UU 300
#define G4 1200   // 4*U
#define NTOK 3

#define KB   10    // blocks per direction
#define UPB  30    // units per block
#define NCOL 120   // gate-cols per block (4*UPB)
#define NPAD 128   // padded to 8 N-tiles of 16
#define KTILES 10  // K = 320 (300 padded), 10 tiles of 32
#define HSTR 328   // padded k-stride (elems) for LDS rows
#define ZSTR 132
#define HROW 304   // global H row stride (elems), 16B multiple

typedef uint16_t bf16_t;
typedef short  s16x8 __attribute__((ext_vector_type(8)));
typedef float  f32x4 __attribute__((ext_vector_type(4)));

__device__ __forceinline__ float bf2f(uint16_t u) {
    union { uint32_t i; float f; } v; v.i = ((uint32_t)u) << 16; return v.f;
}
__device__ __forceinline__ uint16_t f2bf(float f) {
    union { uint32_t i; float f; } v; v.f = f;
    uint32_t r = v.i + 0x7fffu + ((v.i >> 16) & 1u);   // RNE
    return (uint16_t)(r >> 16);
}
__device__ __forceinline__ float ldf(const void* base, size_t idx, int f32m) {
    return f32m ? ((const float*)base)[idx]
                : bf2f(((const uint16_t*)base)[idx]);
}

// ---------------------------------------------------------------------------
// Kernel 0: dtype detector (f32 vs bf16 inputs).
// ---------------------------------------------------------------------------
__global__ void detect_dtype(const uint16_t* __restrict__ emb_u16,
                             int* __restrict__ flag) {
    __shared__ float red[256];
    const int tid = threadIdx.x;
    float m = 0.f;
    for (int k = tid; k < 4096; k += 256)
        m = fmaxf(m, fabsf(bf2f(emb_u16[2 * k])));
    red[tid] = m;
    __syncthreads();
    for (int s = 128; s > 0; s >>= 1) {
        if (tid < s) red[tid] = fmaxf(red[tid], red[tid + s]);
        __syncthreads();
    }
    if (tid == 0) flag[0] = (red[0] > 1.0e3f) ? 1 : 0;
}

// ---------------------------------------------------------------------------
// Kernel 1: build WrPT[dir][p][k]: p = 4u+g (gate-interleaved), k-major rows
// of length 304 (k>=300 zero).  WrPT[p][k] = Wr[k][g*300+u].
// ---------------------------------------------------------------------------
__global__ void prep_wrp(const void* __restrict__ Wr_f,
                         const void* __restrict__ Wr_b,
                         bf16_t* __restrict__ WrPT_f,
                         bf16_t* __restrict__ WrPT_b,
                         const int* __restrict__ flagp) {
    const int f32m = *flagp;
    int idx = blockIdx.x * 256 + threadIdx.x;          // over 1200*304
    const void* src = blockIdx.y ? Wr_b : Wr_f;
    bf16_t*     dst = blockIdx.y ? WrPT_b : WrPT_f;
    if (idx < G4 * HROW) {
        int p = idx / HROW;
        int k = idx - p * HROW;
        int u = p >> 2, g = p & 3;
        float v = (k < DD) ? ldf(src, (size_t)k * G4 + g * UU + u, f32m) : 0.f;
        dst[idx] = f2bf(v);
    }
}

// ---------------------------------------------------------------------------
// Kernel 1b: zero H double-buffers and barrier counters.
// ---------------------------------------------------------------------------
__global__ void init_state(bf16_t* __restrict__ Hglob, int* __restrict__ done) {
    int i = blockIdx.x * 256 + threadIdx.x;
    if (i < 2 * 2 * BB * HROW) Hglob[i] = 0;
    if (i < 2 * TT) done[i] = 0;
}

// ---------------------------------------------------------------------------
// Kernel 2: zx[r][p] = sum_d emb[inputs[r]][d] * Wk[d][j] + b[j], stored at
// permuted col p = 4*(j%300) + j/300.  bf16 out.
// ---------------------------------------------------------------------------
#define BM 64
#define BN 64
#define BK 16
__global__ __launch_bounds__(256) void zx_gemm(
    const int* __restrict__ inputs, const void* __restrict__ emb,
    const void* __restrict__ Wk_f, const void* __restrict__ b_f,
    const void* __restrict__ Wk_b, const void* __restrict__ b_b,
    bf16_t* __restrict__ zxf, bf16_t* __restrict__ zxb,
    const int* __restrict__ flagp) {

    const int f32m = *flagp;
    const int dir = blockIdx.z;
    const void* Wk   = dir ? Wk_b : Wk_f;
    const void* bias = dir ? b_b  : b_f;
    bf16_t*     out  = dir ? zxb  : zxf;

    __shared__ __align__(16) float As[BM][BK + 1];
    __shared__ __align__(16) float Bs[BK][BN];
    __shared__ int rowids[BM];

    const int tid = threadIdx.x;
    const int rowBase = blockIdx.y * BM;
    const int colBase = blockIdx.x * BN;

    if (tid < BM) rowids[tid] = inputs[rowBase + tid];
    __syncthreads();

    float acc[4][4] = {};
    const int tx = tid & 15;
    const int ty = tid >> 4;

    for (int k0 = 0; k0 < DD; k0 += BK) {
#pragma unroll
        for (int i = 0; i < 4; i++) {
            int idx = tid + i * 256;
            int r = idx >> 4, k = idx & 15;
            int kk = k0 + k;
            float v = 0.f;
            if (kk < DD) v = ldf(emb, (size_t)rowids[r] * DD + kk, f32m);
            As[r][k] = v;
        }
#pragma unroll
        for (int i = 0; i < 4; i++) {
            int idx = tid + i * 256;
            int k = idx >> 6, c = idx & 63;
            int kk = k0 + k;
            int col = colBase + c;
            float v = 0.f;
            if (kk < DD && col < G4) v = ldf(Wk, (size_t)kk * G4 + col, f32m);
            Bs[k][c] = v;
        }
        __syncthreads();
#pragma unroll
        for (int k = 0; k < BK; k++) {
            float a0 = As[ty * 4 + 0][k];
            float a1 = As[ty * 4 + 1][k];
            float a2 = As[ty * 4 + 2][k];
            float a3 = As[ty * 4 + 3][k];
            float4 b4 = *(const float4*)&Bs[k][tx * 4];
            acc[0][0] += a0 * b4.x; acc[0][1] += a0 * b4.y; acc[0][2] += a0 * b4.z; acc[0][3] += a0 * b4.w;
            acc[1][0] += a1 * b4.x; acc[1][1] += a1 * b4.y; acc[1][2] += a1 * b4.z; acc[1][3] += a1 * b4.w;
            acc[2][0] += a2 * b4.x; acc[2][1] += a2 * b4.y; acc[2][2] += a2 * b4.z; acc[2][3] += a2 * b4.w;
            acc[3][0] += a3 * b4.x; acc[3][1] += a3 * b4.y; acc[3][2] += a3 * b4.z; acc[3][3] += a3 * b4.w;
        }
        __syncthreads();
    }

#pragma unroll
    for (int i = 0; i < 4; i++) {
        int r = rowBase + ty * 4 + i;
#pragma unroll
        for (int jj = 0; jj < 4; jj++) {
            int col = colBase + tx * 4 + jj;
            if (col < G4) {
                int u = col % UU, g = col / UU;
                int p = 4 * u + g;
                out[(size_t)r * G4 + p] = f2bf(acc[i][jj] + ldf(bias, col, f32m));
            }
        }
    }
}

// ---------------------------------------------------------------------------
// Kernel 3: batched MFMA recurrence.  grid = 20 blocks (10 per dir), 256 thr.
// ---------------------------------------------------------------------------
__global__ __launch_bounds__(256) void lstm_rec2(
    const bf16_t* __restrict__ zxf, const bf16_t* __restrict__ zxb,
    const bf16_t* __restrict__ WrPT_f, const bf16_t* __restrict__ WrPT_b,
    const int* __restrict__ seqlen,
    bf16_t* __restrict__ Hglob, int* __restrict__ done,
    bf16_t* __restrict__ hf, bf16_t* __restrict__ hb) {

    const int blk = blockIdx.x % KB;
    const int dir = blockIdx.x / KB;
    const bf16_t* zx   = dir ? zxb    : zxf;
    const bf16_t* WrPT = dir ? WrPT_b : WrPT_f;
    bf16_t*       hout = dir ? hb : hf;
    bf16_t*       Hg   = Hglob + (size_t)dir * (2 * BB * HROW);
    int*          dctr = done + dir * TT;

    __shared__ __align__(16) uint16_t Wlds[NPAD * HSTR];  // 83,968 B
    __shared__ __align__(16) uint16_t Hlds[BB * HSTR];    // 20,992 B
    __shared__ __align__(16) float    zlds[BB * ZSTR];    // 16,896 B
    __shared__ float clds[BB * UPB];                      //  3,840 B
    __shared__ int   sL[BB];

    const int tid = threadIdx.x;

    // one-time init: zero weight LDS AND the full Hlds (its K-pad region
    // [304,328) per row is read by the kt=9 MFMA and must be 0, not garbage).
    for (int i = tid; i < NPAD * HSTR; i += 256) Wlds[i] = 0;
    for (int i = tid; i < BB * HSTR; i += 256) Hlds[i] = 0;
    __syncthreads();
    for (int i = tid; i < NCOL * 38; i += 256) {          // 38 uint4 per col
        int c = i / 38, x = i - c * 38;
        *(uint4*)&Wlds[c * HSTR + x * 8] =
            *(const uint4*)&WrPT[(size_t)(NCOL * blk + c) * HROW + x * 8];
    }
    for (int i = tid; i < BB * UPB; i += 256) clds[i] = 0.f;
    if (tid < BB) sL[tid] = seqlen[tid];
    __syncthreads();

    const int lane = tid & 63;
    const int wv   = tid >> 6;       // wave id 0..3 -> owns cols [32wv,32wv+32)
    const int q    = lane >> 4;      // quad 0..3
    const int c16  = lane & 15;
    const int n0   = 32 * wv;

    for (int ts = 0; ts < TT; ts++) {
        const int t = dir ? (TT - 1 - ts) : ts;

        if (ts > 0) {
            if (tid == 0) {
                while (__hip_atomic_load(&dctr[ts - 1], __ATOMIC_ACQUIRE,
                                         __HIP_MEMORY_SCOPE_AGENT) < KB)
                    __builtin_amdgcn_s_sleep(1);
            }
            __syncthreads();
            __threadfence();
        }

        // load H_ts (32 x 304 bf16) into padded LDS rows (pad stays 0)
        const bf16_t* Hsrc = Hg + (size_t)(ts & 1) * (BB * HROW);
        for (int i = tid; i < BB * 38; i += 256) {
            int b = i / 38, x = i - b * 38;
            *(uint4*)&Hlds[b * HSTR + x * 8] =
                *(const uint4*)&Hsrc[b * HROW + x * 8];
        }

        // prefetch this step's zx slice for the gate phase
        uint2 zpre[4];
#pragma unroll
        for (int it = 0; it < 4; it++) {
            int w = tid + 256 * it;
            if (w < BB * UPB) {
                int b = w / UPB, ul = w - b * UPB;
                zpre[it] = *(const uint2*)&zx[((size_t)(b * TT + t)) * G4 +
                                              NCOL * blk + 4 * ul];
            }
        }
        __syncthreads();

        // z = H @ Wr_slice via MFMA (M=32, N=128, K=320)
        f32x4 acc00 = {0.f,0.f,0.f,0.f}, acc01 = {0.f,0.f,0.f,0.f};
        f32x4 acc10 = {0.f,0.f,0.f,0.f}, acc11 = {0.f,0.f,0.f,0.f};
#pragma unroll
        for (int kt = 0; kt < KTILES; kt++) {
            int k0 = kt * 32 + q * 8;
            s16x8 a0 = *(const s16x8*)&Hlds[c16 * HSTR + k0];
            s16x8 a1 = *(const s16x8*)&Hlds[(c16 + 16) * HSTR + k0];
            s16x8 b0 = *(const s16x8*)&Wlds[(n0 + c16) * HSTR + k0];
            s16x8 b1 = *(const s16x8*)&Wlds[(n0 + 16 + c16) * HSTR + k0];
            acc00 = __builtin_amdgcn_mfma_f32_16x16x32_bf16(a0, b0, acc00, 0, 0, 0);
            acc01 = __builtin_amdgcn_mfma_f32_16x16x32_bf16(a0, b1, acc01, 0, 0, 0);
            acc10 = __builtin_amdgcn_mfma_f32_16x16x32_bf16(a1, b0, acc10, 0, 0, 0);
            acc11 = __builtin_amdgcn_mfma_f32_16x16x32_bf16(a1, b1, acc11, 0, 0, 0);
        }
#pragma unroll
        for (int r = 0; r < 4; r++) {
            int row = 4 * q + r;
            zlds[row * ZSTR + n0 + c16]             = acc00[r];
            zlds[row * ZSTR + n0 + 16 + c16]        = acc01[r];
            zlds[(16 + row) * ZSTR + n0 + c16]      = acc10[r];
            zlds[(16 + row) * ZSTR + n0 + 16 + c16] = acc11[r];
        }
        __syncthreads();

        // gates + state update for 32 batches x our 30 units
        bf16_t* Hdst = Hg + (size_t)((ts + 1) & 1) * (BB * HROW);
#pragma unroll
        for (int it = 0; it < 4; it++) {
            int w = tid + 256 * it;
            if (w < BB * UPB) {
                int b = w / UPB, ul = w - b * UPB;
                float4 z4 = *(const float4*)&zlds[b * ZSTR + 4 * ul];
                uint2 zp = zpre[it];
                float zi = z4.x + bf2f((uint16_t)(zp.x & 0xffff));
                float zf = z4.y + bf2f((uint16_t)(zp.x >> 16));
                float zg = z4.z + bf2f((uint16_t)(zp.y & 0xffff));
                float zo = z4.w + bf2f((uint16_t)(zp.y >> 16));
                float si = 1.f / (1.f + __expf(-zi));
                float sf = 1.f / (1.f + __expf(-zf));
                float so = 1.f / (1.f + __expf(-zo));
                float tg = tanhf(zg);
                float cold = clds[w];
                float cn = sf * cold + si * tg;
                float hn = so * tanhf(cn);
                bool m = (t < sL[b]);
                float hold = bf2f(Hlds[b * HSTR + UPB * blk + ul]);
                float hw = m ? hn : hold;
                clds[w] = m ? cn : cold;
                bf16_t h16 = f2bf(hw);
                Hdst[b * HROW + UPB * blk + ul] = h16;
                hout[((size_t)(b * TT + t)) * UU + UPB * blk + ul] = h16;
            }
        }

        __threadfence();
        __syncthreads();
        if (tid == 0)
            __hip_atomic_fetch_add(&dctr[ts], 1, __ATOMIC_RELEASE,
                                   __HIP_MEMORY_SCOPE_AGENT);
    }
}

// ---------------------------------------------------------------------------
// Kernel 4: out[r] = [hf[r] ; hb[r]] @ fc_W + fc_b.
// ---------------------------------------------------------------------------
__global__ __launch_bounds__(256) void fc_out(
    const bf16_t* __restrict__ hf, const bf16_t* __restrict__ hb,
    const void* __restrict__ fcW, const void* __restrict__ fcb,
    void* __restrict__ out, const int* __restrict__ flagp) {

    const int f32m = *flagp;
    __shared__ float W[2 * UU * NTOK];
    __shared__ float bias[NTOK];
    const int tid = threadIdx.x;
    for (int i = tid; i < 2 * UU * NTOK; i += 256) W[i] = ldf(fcW, i, f32m);
    if (tid < NTOK) bias[tid] = ldf(fcb, tid, f32m);
    __syncthreads();

    const int r = blockIdx.x * 256 + tid;
    const bf16_t* hfr = hf + (size_t)r * UU;
    const bf16_t* hbr = hb + (size_t)r * UU;
    float s0 = bias[0], s1 = bias[1], s2 = bias[2];
    for (int u = 0; u < UU; u++) {
        float f = bf2f(hfr[u]);
        s0 += f * W[u * 3 + 0];
        s1 += f * W[u * 3 + 1];
        s2 += f * W[u * 3 + 2];
    }
    for (int u = 0; u < UU; u++) {
        float f = bf2f(hbr[u]);
        s0 += f * W[(UU + u) * 3 + 0];
        s1 += f * W[(UU + u) * 3 + 1];
        s2 += f * W[(UU + u) * 3 + 2];
    }
    if (f32m) {
        float* o = (float*)out;
        o[(size_t)r * 3 + 0] = s0;
        o[(size_t)r * 3 + 1] = s1;
        o[(size_t)r * 3 + 2] = s2;
    } else {
        bf16_t* o = (bf16_t*)out;
        o[(size_t)r * 3 + 0] = f2bf(s0);
        o[(size_t)r * 3 + 1] = f2bf(s1);
        o[(size_t)r * 3 + 2] = f2bf(s2);
    }
}

// ---------------------------------------------------------------------------
extern "C" void kernel_launch(void* const* d_in, const int* in_sizes, int n_in,
                              void* d_out, int out_size, void* d_ws, size_t ws_size,
                              hipStream_t stream) {
    const int* inputs = (const int*)d_in[0];
    const int* seqlen = (const int*)d_in[1];
    const void* emb  = d_in[2];
    const void* Wk_f = d_in[3];
    const void* Wr_f = d_in[4];
    const void* b_f  = d_in[5];
    const void* Wk_b = d_in[6];
    const void* Wr_b = d_in[7];
    const void* b_b  = d_in[8];
    const void* fcW  = d_in[9];
    const void* fcb  = d_in[10];

    // workspace layout (bytes), 16B aligned
    char* ws = (char*)d_ws;
    int*    flag  = (int*)(ws + 0);                  // 64 B
    int*    done  = (int*)(ws + 64);                 // 1024*4 = 4096
    bf16_t* Hglob = (bf16_t*)(ws + 4224);            // 2*2*32*304*2 = 155,648
    bf16_t* WrPT_f= (bf16_t*)(ws + 159872);          // 729,600
    bf16_t* WrPT_b= (bf16_t*)(ws + 889472);          // 729,600
    bf16_t* zxPf  = (bf16_t*)(ws + 1619072);         // 39,321,600
    bf16_t* zxPb  = (bf16_t*)(ws + 40940672);        // 39,321,600
    bf16_t* hfbuf = (bf16_t*)(ws + 80262272);        // 9,830,400
    bf16_t* hbbuf = (bf16_t*)(ws + 90092672);        // 9,830,400 -> 99,923,072

    detect_dtype<<<1, 256, 0, stream>>>((const uint16_t*)emb, flag);
    {
        dim3 grid((G4 * HROW + 255) / 256, 2);
        prep_wrp<<<grid, 256, 0, stream>>>(Wr_f, Wr_b, WrPT_f, WrPT_b, flag);
    }
    init_state<<<(2 * 2 * BB * HROW + 255) / 256, 256, 0, stream>>>(Hglob, done);
    {
        dim3 grid((G4 + BN - 1) / BN, (BB * TT) / BM, 2);
        zx_gemm<<<grid, 256, 0, stream>>>(inputs, emb, Wk_f, b_f, Wk_b, b_b,
                                          zxPf, zxPb, flag);
    }
    lstm_rec2<<<2 * KB, 256, 0, stream>>>(zxPf, zxPb, WrPT_f, WrPT_b, seqlen,
                                          Hglob, done, hfbuf, hbbuf);
    fc_out<<<(BB * TT) / 256, 256, 0, stream>>>(hfbuf, hbbuf, fcW, fcb,
                                                d_out, flag);
}

// Round 5
// 4158.419 us; speedup vs baseline: 2.8328x; 1.3029x over previous
//
#include <hip/hip_runtime.h>
#include <stdint.h>

// Bidirectional LSTM.  B=32, T=512, V=32000, D=300, U=300, NT=3.
// R5: recurrence communication rebuilt on write-through agent-scope relaxed
// atomics (sc0/sc1 -> coherent at L3), eliminating per-step __threadfence
// L2 invalidate/writeback.  zx prefetch hoisted above the spin.

#define BB 32
#define TT 512
#define DD 300
#define UU 300
#define G4 1200   // 4*U
#define NTOK 3

#define KB   10    // blocks per direction
#define UPB  30    // units per block
#define NCOL 120   // gate-cols per block (4*UPB)
#define NPAD 128   // padded to 8 N-tiles of 16
#define KTILES 10  // K = 320 (300 padded), 10 tiles of 32
#define HSTR 328   // padded k-stride (elems) for LDS rows
#define ZSTR 132
#define HROW 304   // global H row stride (elems), 16B multiple

typedef uint16_t bf16_t;
typedef short  s16x8 __attribute__((ext_vector_type(8)));
typedef float  f32x4 __attribute__((ext_vector_type(4)));

__device__ __forceinline__ float bf2f(uint16_t u) {
    union { uint32_t i; float f; } v; v.i = ((uint32_t)u) << 16; return v.f;
}
__device__ __forceinline__ uint16_t f2bf(float f) {
    union { uint32_t i; float f; } v; v.f = f;
    uint32_t r = v.i + 0x7fffu + ((v.i >> 16) & 1u);   // RNE
    return (uint16_t)(r >> 16);
}
__device__ __forceinline__ float ldf(const void* base, size_t idx, int f32m) {
    return f32m ? ((const float*)base)[idx]
                : bf2f(((const uint16_t*)base)[idx]);
}

// ---------------------------------------------------------------------------
// Kernel 0: dtype detector (f32 vs bf16 inputs).
// ---------------------------------------------------------------------------
__global__ void detect_dtype(const uint16_t* __restrict__ emb_u16,
                             int* __restrict__ flag) {
    __shared__ float red[256];
    const int tid = threadIdx.x;
    float m = 0.f;
    for (int k = tid; k < 4096; k += 256)
        m = fmaxf(m, fabsf(bf2f(emb_u16[2 * k])));
    red[tid] = m;
    __syncthreads();
    for (int s = 128; s > 0; s >>= 1) {
        if (tid < s) red[tid] = fmaxf(red[tid], red[tid + s]);
        __syncthreads();
    }
    if (tid == 0) flag[0] = (red[0] > 1.0e3f) ? 1 : 0;
}

// ---------------------------------------------------------------------------
// Kernel 1: build WrPT[dir][p][k]: p = 4u+g (gate-interleaved), k-major rows
// of length 304 (k>=300 zero).  WrPT[p][k] = Wr[k][g*300+u].
// ---------------------------------------------------------------------------
__global__ void prep_wrp(const void* __restrict__ Wr_f,
                         const void* __restrict__ Wr_b,
                         bf16_t* __restrict__ WrPT_f,
                         bf16_t* __restrict__ WrPT_b,
                         const int* __restrict__ flagp) {
    const int f32m = *flagp;
    int idx = blockIdx.x * 256 + threadIdx.x;          // over 1200*304
    const void* src = blockIdx.y ? Wr_b : Wr_f;
    bf16_t*     dst = blockIdx.y ? WrPT_b : WrPT_f;
    if (idx < G4 * HROW) {
        int p = idx / HROW;
        int k = idx - p * HROW;
        int u = p >> 2, g = p & 3;
        float v = (k < DD) ? ldf(src, (size_t)k * G4 + g * UU + u, f32m) : 0.f;
        dst[idx] = f2bf(v);
    }
}

// ---------------------------------------------------------------------------
// Kernel 1b: zero H double-buffers and barrier counters.
// ---------------------------------------------------------------------------
__global__ void init_state(bf16_t* __restrict__ Hglob, int* __restrict__ done) {
    int i = blockIdx.x * 256 + threadIdx.x;
    if (i < 2 * 2 * BB * HROW) Hglob[i] = 0;
    if (i < 2 * TT) done[i] = 0;
}

// ---------------------------------------------------------------------------
// Kernel 2: zx[r][p] = sum_d emb[inputs[r]][d] * Wk[d][j] + b[j], stored at
// permuted col p = 4*(j%300) + j/300.  bf16 out.
// ---------------------------------------------------------------------------
#define BM 64
#define BN 64
#define BK 16
__global__ __launch_bounds__(256) void zx_gemm(
    const int* __restrict__ inputs, const void* __restrict__ emb,
    const void* __restrict__ Wk_f, const void* __restrict__ b_f,
    const void* __restrict__ Wk_b, const void* __restrict__ b_b,
    bf16_t* __restrict__ zxf, bf16_t* __restrict__ zxb,
    const int* __restrict__ flagp) {

    const int f32m = *flagp;
    const int dir = blockIdx.z;
    const void* Wk   = dir ? Wk_b : Wk_f;
    const void* bias = dir ? b_b  : b_f;
    bf16_t*     out  = dir ? zxb  : zxf;

    __shared__ __align__(16) float As[BM][BK + 1];
    __shared__ __align__(16) float Bs[BK][BN];
    __shared__ int rowids[BM];

    const int tid = threadIdx.x;
    const int rowBase = blockIdx.y * BM;
    const int colBase = blockIdx.x * BN;

    if (tid < BM) rowids[tid] = inputs[rowBase + tid];
    __syncthreads();

    float acc[4][4] = {};
    const int tx = tid & 15;
    const int ty = tid >> 4;

    for (int k0 = 0; k0 < DD; k0 += BK) {
#pragma unroll
        for (int i = 0; i < 4; i++) {
            int idx = tid + i * 256;
            int r = idx >> 4, k = idx & 15;
            int kk = k0 + k;
            float v = 0.f;
            if (kk < DD) v = ldf(emb, (size_t)rowids[r] * DD + kk, f32m);
            As[r][k] = v;
        }
#pragma unroll
        for (int i = 0; i < 4; i++) {
            int idx = tid + i * 256;
            int k = idx >> 6, c = idx & 63;
            int kk = k0 + k;
            int col = colBase + c;
            float v = 0.f;
            if (kk < DD && col < G4) v = ldf(Wk, (size_t)kk * G4 + col, f32m);
            Bs[k][c] = v;
        }
        __syncthreads();
#pragma unroll
        for (int k = 0; k < BK; k++) {
            float a0 = As[ty * 4 + 0][k];
            float a1 = As[ty * 4 + 1][k];
            float a2 = As[ty * 4 + 2][k];
            float a3 = As[ty * 4 + 3][k];
            float4 b4 = *(const float4*)&Bs[k][tx * 4];
            acc[0][0] += a0 * b4.x; acc[0][1] += a0 * b4.y; acc[0][2] += a0 * b4.z; acc[0][3] += a0 * b4.w;
            acc[1][0] += a1 * b4.x; acc[1][1] += a1 * b4.y; acc[1][2] += a1 * b4.z; acc[1][3] += a1 * b4.w;
            acc[2][0] += a2 * b4.x; acc[2][1] += a2 * b4.y; acc[2][2] += a2 * b4.z; acc[2][3] += a2 * b4.w;
            acc[3][0] += a3 * b4.x; acc[3][1] += a3 * b4.y; acc[3][2] += a3 * b4.z; acc[3][3] += a3 * b4.w;
        }
        __syncthreads();
    }

#pragma unroll
    for (int i = 0; i < 4; i++) {
        int r = rowBase + ty * 4 + i;
#pragma unroll
        for (int jj = 0; jj < 4; jj++) {
            int col = colBase + tx * 4 + jj;
            if (col < G4) {
                int u = col % UU, g = col / UU;
                int p = 4 * u + g;
                out[(size_t)r * G4 + p] = f2bf(acc[i][jj] + ldf(bias, col, f32m));
            }
        }
    }
}

// ---------------------------------------------------------------------------
// Kernel 3: batched MFMA recurrence.  grid = 20 blocks (10 per dir), 256 thr.
// Cross-block H exchange via agent-scope relaxed atomics (write-through, L3
// coherent) — no fences, no L2 invalidate/writeback in the step loop.
// ---------------------------------------------------------------------------
__global__ __launch_bounds__(256) void lstm_rec2(
    const bf16_t* __restrict__ zxf, const bf16_t* __restrict__ zxb,
    const bf16_t* __restrict__ WrPT_f, const bf16_t* __restrict__ WrPT_b,
    const int* __restrict__ seqlen,
    bf16_t* __restrict__ Hglob, int* __restrict__ done,
    bf16_t* __restrict__ hf, bf16_t* __restrict__ hb) {

    const int blk = blockIdx.x % KB;
    const int dir = blockIdx.x / KB;
    const bf16_t* zx   = dir ? zxb    : zxf;
    const bf16_t* WrPT = dir ? WrPT_b : WrPT_f;
    bf16_t*       hout = dir ? hb : hf;
    bf16_t*       Hg   = Hglob + (size_t)dir * (2 * BB * HROW);
    int*          dctr = done + dir * TT;

    __shared__ __align__(16) uint16_t Wlds[NPAD * HSTR];  // 83,968 B
    __shared__ __align__(16) uint16_t Hlds[BB * HSTR];    // 20,992 B
    __shared__ __align__(16) float    zlds[BB * ZSTR];    // 16,896 B
    __shared__ float    clds[BB * UPB];                   //  3,840 B
    __shared__ uint16_t hstage[BB * UPB];                 //  1,920 B
    __shared__ int      sL[BB];

    const int tid = threadIdx.x;

    // one-time init: zero weight LDS AND full Hlds (K-pad region [304,328)
    // per row is read by the kt=9 MFMA and must be 0).
    for (int i = tid; i < NPAD * HSTR; i += 256) Wlds[i] = 0;
    for (int i = tid; i < BB * HSTR; i += 256) Hlds[i] = 0;
    __syncthreads();
    for (int i = tid; i < NCOL * 38; i += 256) {          // 38 uint4 per col
        int c = i / 38, x = i - c * 38;
        *(uint4*)&Wlds[c * HSTR + x * 8] =
            *(const uint4*)&WrPT[(size_t)(NCOL * blk + c) * HROW + x * 8];
    }
    for (int i = tid; i < BB * UPB; i += 256) clds[i] = 0.f;
    if (tid < BB) sL[tid] = seqlen[tid];
    __syncthreads();

    const int lane = tid & 63;
    const int wv   = tid >> 6;       // wave id 0..3 -> owns cols [32wv,32wv+32)
    const int q    = lane >> 4;      // quad 0..3
    const int c16  = lane & 15;
    const int n0   = 32 * wv;

    for (int ts = 0; ts < TT; ts++) {
        const int t = dir ? (TT - 1 - ts) : ts;

        // zx prefetch FIRST — block-private, overlaps the barrier wait
        uint2 zpre[4];
#pragma unroll
        for (int it = 0; it < 4; it++) {
            int w = tid + 256 * it;
            if (w < BB * UPB) {
                int b = w / UPB, ul = w - b * UPB;
                zpre[it] = *(const uint2*)&zx[((size_t)(b * TT + t)) * G4 +
                                              NCOL * blk + 4 * ul];
            }
        }

        if (ts > 0) {
            if (tid == 0) {
                while (__hip_atomic_load(&dctr[ts - 1], __ATOMIC_RELAXED,
                                         __HIP_MEMORY_SCOPE_AGENT) < KB)
                    __builtin_amdgcn_s_sleep(1);
            }
            __syncthreads();
        }

        // load H_ts (32 x 304 bf16) via agent-coherent u64 atomic loads
        const unsigned long long* Hsrc64 =
            (const unsigned long long*)(Hg + (size_t)(ts & 1) * (BB * HROW));
        for (int i = tid; i < BB * 76; i += 256) {        // 76 u64 per row
            int b = i / 76, x = i - b * 76;
            unsigned long long v = __hip_atomic_load(
                &Hsrc64[(size_t)b * 76 + x], __ATOMIC_RELAXED,
                __HIP_MEMORY_SCOPE_AGENT);
            *(unsigned long long*)&Hlds[b * HSTR + x * 4] = v;
        }
        __syncthreads();

        // z = H @ Wr_slice via MFMA (M=32, N=128, K=320)
        f32x4 acc00 = {0.f,0.f,0.f,0.f}, acc01 = {0.f,0.f,0.f,0.f};
        f32x4 acc10 = {0.f,0.f,0.f,0.f}, acc11 = {0.f,0.f,0.f,0.f};
#pragma unroll
        for (int kt = 0; kt < KTILES; kt++) {
            int k0 = kt * 32 + q * 8;
            s16x8 a0 = *(const s16x8*)&Hlds[c16 * HSTR + k0];
            s16x8 a1 = *(const s16x8*)&Hlds[(c16 + 16) * HSTR + k0];
            s16x8 b0 = *(const s16x8*)&Wlds[(n0 + c16) * HSTR + k0];
            s16x8 b1 = *(const s16x8*)&Wlds[(n0 + 16 + c16) * HSTR + k0];
            acc00 = __builtin_amdgcn_mfma_f32_16x16x32_bf16(a0, b0, acc00, 0, 0, 0);
            acc01 = __builtin_amdgcn_mfma_f32_16x16x32_bf16(a0, b1, acc01, 0, 0, 0);
            acc10 = __builtin_amdgcn_mfma_f32_16x16x32_bf16(a1, b0, acc10, 0, 0, 0);
            acc11 = __builtin_amdgcn_mfma_f32_16x16x32_bf16(a1, b1, acc11, 0, 0, 0);
        }
#pragma unroll
        for (int r = 0; r < 4; r++) {
            int row = 4 * q + r;
            zlds[row * ZSTR + n0 + c16]             = acc00[r];
            zlds[row * ZSTR + n0 + 16 + c16]        = acc01[r];
            zlds[(16 + row) * ZSTR + n0 + c16]      = acc10[r];
            zlds[(16 + row) * ZSTR + n0 + 16 + c16] = acc11[r];
        }
        __syncthreads();

        // gates + state update for 32 batches x our 30 units
#pragma unroll
        for (int it = 0; it < 4; it++) {
            int w = tid + 256 * it;
            if (w < BB * UPB) {
                int b = w / UPB, ul = w - b * UPB;
                float4 z4 = *(const float4*)&zlds[b * ZSTR + 4 * ul];
                uint2 zp = zpre[it];
                float zi = z4.x + bf2f((uint16_t)(zp.x & 0xffff));
                float zf = z4.y + bf2f((uint16_t)(zp.x >> 16));
                float zg = z4.z + bf2f((uint16_t)(zp.y & 0xffff));
                float zo = z4.w + bf2f((uint16_t)(zp.y >> 16));
                float si = 1.f / (1.f + __expf(-zi));
                float sf = 1.f / (1.f + __expf(-zf));
                float so = 1.f / (1.f + __expf(-zo));
                float tg = tanhf(zg);
                float cold = clds[w];
                float cn = sf * cold + si * tg;
                float hn = so * tanhf(cn);
                bool m = (t < sL[b]);
                float hold = bf2f(Hlds[b * HSTR + UPB * blk + ul]);
                float hw = m ? hn : hold;
                clds[w] = m ? cn : cold;
                bf16_t h16 = f2bf(hw);
                hstage[w] = h16;
                hout[((size_t)(b * TT + t)) * UU + UPB * blk + ul] = h16;  // private
            }
        }
        __syncthreads();

        // publish our H columns: paired u32 write-through atomic stores
        bf16_t* Hdst = Hg + (size_t)((ts + 1) & 1) * (BB * HROW);
        for (int i = tid; i < BB * (UPB / 2); i += 256) { // 480 pairs
            int b = i / (UPB / 2), k = i - b * (UPB / 2);
            uint32_t val = (uint32_t)hstage[b * UPB + 2 * k] |
                           ((uint32_t)hstage[b * UPB + 2 * k + 1] << 16);
            __hip_atomic_store(
                (uint32_t*)&Hdst[b * HROW + UPB * blk + 2 * k], val,
                __ATOMIC_RELAXED, __HIP_MEMORY_SCOPE_AGENT);
        }
        __builtin_amdgcn_s_waitcnt(0);   // our stores acked at coherence point
        __syncthreads();                  // all waves' stores drained
        if (tid == 0)
            __hip_atomic_fetch_add(&dctr[ts], 1, __ATOMIC_RELAXED,
                                   __HIP_MEMORY_SCOPE_AGENT);
    }
}

// ---------------------------------------------------------------------------
// Kernel 4: out[r] = [hf[r] ; hb[r]] @ fc_W + fc_b.
// ---------------------------------------------------------------------------
__global__ __launch_bounds__(256) void fc_out(
    const bf16_t* __restrict__ hf, const bf16_t* __restrict__ hb,
    const void* __restrict__ fcW, const void* __restrict__ fcb,
    void* __restrict__ out, const int* __restrict__ flagp) {

    const int f32m = *flagp;
    __shared__ float W[2 * UU * NTOK];
    __shared__ float bias[NTOK];
    const int tid = threadIdx.x;
    for (int i = tid; i < 2 * UU * NTOK; i += 256) W[i] = ldf(fcW, i, f32m);
    if (tid < NTOK) bias[tid] = ldf(fcb, tid, f32m);
    __syncthreads();

    const int r = blockIdx.x * 256 + tid;
    const bf16_t* hfr = hf + (size_t)r * UU;
    const bf16_t* hbr = hb + (size_t)r * UU;
    float s0 = bias[0], s1 = bias[1], s2 = bias[2];
    for (int u = 0; u < UU; u++) {
        float f = bf2f(hfr[u]);
        s0 += f * W[u * 3 + 0];
        s1 += f * W[u * 3 + 1];
        s2 += f * W[u * 3 + 2];
    }
    for (int u = 0; u < UU; u++) {
        float f = bf2f(hbr[u]);
        s0 += f * W[(UU + u) * 3 + 0];
        s1 += f * W[(UU + u) * 3 + 1];
        s2 += f * W[(UU + u) * 3 + 2];
    }
    if (f32m) {
        float* o = (float*)out;
        o[(size_t)r * 3 + 0] = s0;
        o[(size_t)r * 3 + 1] = s1;
        o[(size_t)r * 3 + 2] = s2;
    } else {
        bf16_t* o = (bf16_t*)out;
        o[(size_t)r * 3 + 0] = f2bf(s0);
        o[(size_t)r * 3 + 1] = f2bf(s1);
        o[(size_t)r * 3 + 2] = f2bf(s2);
    }
}

// ---------------------------------------------------------------------------
extern "C" void kernel_launch(void* const* d_in, const int* in_sizes, int n_in,
                              void* d_out, int out_size, void* d_ws, size_t ws_size,
                              hipStream_t stream) {
    const int* inputs = (const int*)d_in[0];
    const int* seqlen = (const int*)d_in[1];
    const void* emb  = d_in[2];
    const void* Wk_f = d_in[3];
    const void* Wr_f = d_in[4];
    const void* b_f  = d_in[5];
    const void* Wk_b = d_in[6];
    const void* Wr_b = d_in[7];
    const void* b_b  = d_in[8];
    const void* fcW  = d_in[9];
    const void* fcb  = d_in[10];

    // workspace layout (bytes), 16B aligned
    char* ws = (char*)d_ws;
    int*    flag  = (int*)(ws + 0);                  // 64 B
    int*    done  = (int*)(ws + 64);                 // 4096
    bf16_t* Hglob = (bf16_t*)(ws + 4224);            // 155,648
    bf16_t* WrPT_f= (bf16_t*)(ws + 159872);          // 729,600
    bf16_t* WrPT_b= (bf16_t*)(ws + 889472);          // 729,600
    bf16_t* zxPf  = (bf16_t*)(ws + 1619072);         // 39,321,600
    bf16_t* zxPb  = (bf16_t*)(ws + 40940672);        // 39,321,600
    bf16_t* hfbuf = (bf16_t*)(ws + 80262272);        // 9,830,400
    bf16_t* hbbuf = (bf16_t*)(ws + 90092672);        // 9,830,400 -> 99,923,072

    detect_dtype<<<1, 256, 0, stream>>>((const uint16_t*)emb, flag);
    {
        dim3 grid((G4 * HROW + 255) / 256, 2);
        prep_wrp<<<grid, 256, 0, stream>>>(Wr_f, Wr_b, WrPT_f, WrPT_b, flag);
    }
    init_state<<<(2 * 2 * BB * HROW + 255) / 256, 256, 0, stream>>>(Hglob, done);
    {
        dim3 grid((G4 + BN - 1) / BN, (BB * TT) / BM, 2);
        zx_gemm<<<grid, 256, 0, stream>>>(inputs, emb, Wk_f, b_f, Wk_b, b_b,
                                          zxPf, zxPb, flag);
    }
    lstm_rec2<<<2 * KB, 256, 0, stream>>>(zxPf, zxPb, WrPT_f, WrPT_b, seqlen,
                                          Hglob, done, hfbuf, hbbuf);
    fc_out<<<(BB * TT) / 256, 256, 0, stream>>>(hfbuf, hbbuf, fcW, fcb,
                                                d_out, flag);
}

// Round 6
// 2695.379 us; speedup vs baseline: 4.3704x; 1.5428x over previous
//
#include <hip/hip_runtime.h>
#include <stdint.h>

// Bidirectional LSTM.  B=32, T=512, V=32000, D=300, U=300, NT=3.
// R6: recurrence sync rebuilt: per-block ready FLAGS (no shared-counter RMW
// serialization), wave-parallel polling, pipelined u64 H reload, and
// XOR-swizzled LDS tiles (2-way-free bank pattern, 16B-aligned b128).

#define BB 32
#define TT 512
#define DD 300
#define UU 300
#define G4 1200   // 4*U
#define NTOK 3

#define KB   10    // blocks per direction
#define UPB  30    // units per block
#define NCOL 120   // gate-cols per block (4*UPB)
#define NPAD 128   // padded to 4 waves x 32 cols
#define KTILES 10  // K = 320 (300 padded), 10 tiles of 32
#define HSTR 320   // LDS row stride (elems); swizzle provides conflict-freedom
#define ZSTR 132
#define HROW 304   // global H row stride (elems), 16B multiple

typedef uint16_t bf16_t;
typedef short  s16x8 __attribute__((ext_vector_type(8)));
typedef float  f32x4 __attribute__((ext_vector_type(4)));

__device__ __forceinline__ float bf2f(uint16_t u) {
    union { uint32_t i; float f; } v; v.i = ((uint32_t)u) << 16; return v.f;
}
__device__ __forceinline__ uint16_t f2bf(float f) {
    union { uint32_t i; float f; } v; v.f = f;
    uint32_t r = v.i + 0x7fffu + ((v.i >> 16) & 1u);   // RNE
    return (uint16_t)(r >> 16);
}
__device__ __forceinline__ float ldf(const void* base, size_t idx, int f32m) {
    return f32m ? ((const float*)base)[idx]
                : bf2f(((const uint16_t*)base)[idx]);
}
// swizzled LDS element position: rows of HSTR elems, 8-elem groups XORed
__device__ __forceinline__ int swz(int row, int e) {
    return row * HSTR + ((((e >> 3) ^ (row & 7)) << 3) | (e & 7));
}

// ---------------------------------------------------------------------------
// Kernel 0: dtype detector (f32 vs bf16 inputs).
// ---------------------------------------------------------------------------
__global__ void detect_dtype(const uint16_t* __restrict__ emb_u16,
                             int* __restrict__ flag) {
    __shared__ float red[256];
    const int tid = threadIdx.x;
    float m = 0.f;
    for (int k = tid; k < 4096; k += 256)
        m = fmaxf(m, fabsf(bf2f(emb_u16[2 * k])));
    red[tid] = m;
    __syncthreads();
    for (int s = 128; s > 0; s >>= 1) {
        if (tid < s) red[tid] = fmaxf(red[tid], red[tid + s]);
        __syncthreads();
    }
    if (tid == 0) flag[0] = (red[0] > 1.0e3f) ? 1 : 0;
}

// ---------------------------------------------------------------------------
// Kernel 1: build WrPT[dir][p][k]: p = 4u+g (gate-interleaved), k-major rows
// of length 304 (k>=300 zero).  WrPT[p][k] = Wr[k][g*300+u].
// ---------------------------------------------------------------------------
__global__ void prep_wrp(const void* __restrict__ Wr_f,
                         const void* __restrict__ Wr_b,
                         bf16_t* __restrict__ WrPT_f,
                         bf16_t* __restrict__ WrPT_b,
                         const int* __restrict__ flagp) {
    const int f32m = *flagp;
    int idx = blockIdx.x * 256 + threadIdx.x;          // over 1200*304
    const void* src = blockIdx.y ? Wr_b : Wr_f;
    bf16_t*     dst = blockIdx.y ? WrPT_b : WrPT_f;
    if (idx < G4 * HROW) {
        int p = idx / HROW;
        int k = idx - p * HROW;
        int u = p >> 2, g = p & 3;
        float v = (k < DD) ? ldf(src, (size_t)k * G4 + g * UU + u, f32m) : 0.f;
        dst[idx] = f2bf(v);
    }
}

// ---------------------------------------------------------------------------
// Kernel 1b: zero H double-buffers and ready flags.
// ---------------------------------------------------------------------------
__global__ void init_state(bf16_t* __restrict__ Hglob, int* __restrict__ flags) {
    int i = blockIdx.x * 256 + threadIdx.x;
    if (i < 2 * 2 * BB * HROW) Hglob[i] = 0;
    if (i < 2 * TT * 16) flags[i] = 0;
}

// ---------------------------------------------------------------------------
// Kernel 2: zx[r][p] = sum_d emb[inputs[r]][d] * Wk[d][j] + b[j], stored at
// permuted col p = 4*(j%300) + j/300.  bf16 out.
// ---------------------------------------------------------------------------
#define BM 64
#define BN 64
#define BK 16
__global__ __launch_bounds__(256) void zx_gemm(
    const int* __restrict__ inputs, const void* __restrict__ emb,
    const void* __restrict__ Wk_f, const void* __restrict__ b_f,
    const void* __restrict__ Wk_b, const void* __restrict__ b_b,
    bf16_t* __restrict__ zxf, bf16_t* __restrict__ zxb,
    const int* __restrict__ flagp) {

    const int f32m = *flagp;
    const int dir = blockIdx.z;
    const void* Wk   = dir ? Wk_b : Wk_f;
    const void* bias = dir ? b_b  : b_f;
    bf16_t*     out  = dir ? zxb  : zxf;

    __shared__ __align__(16) float As[BM][BK + 1];
    __shared__ __align__(16) float Bs[BK][BN];
    __shared__ int rowids[BM];

    const int tid = threadIdx.x;
    const int rowBase = blockIdx.y * BM;
    const int colBase = blockIdx.x * BN;

    if (tid < BM) rowids[tid] = inputs[rowBase + tid];
    __syncthreads();

    float acc[4][4] = {};
    const int tx = tid & 15;
    const int ty = tid >> 4;

    for (int k0 = 0; k0 < DD; k0 += BK) {
#pragma unroll
        for (int i = 0; i < 4; i++) {
            int idx = tid + i * 256;
            int r = idx >> 4, k = idx & 15;
            int kk = k0 + k;
            float v = 0.f;
            if (kk < DD) v = ldf(emb, (size_t)rowids[r] * DD + kk, f32m);
            As[r][k] = v;
        }
#pragma unroll
        for (int i = 0; i < 4; i++) {
            int idx = tid + i * 256;
            int k = idx >> 6, c = idx & 63;
            int kk = k0 + k;
            int col = colBase + c;
            float v = 0.f;
            if (kk < DD && col < G4) v = ldf(Wk, (size_t)kk * G4 + col, f32m);
            Bs[k][c] = v;
        }
        __syncthreads();
#pragma unroll
        for (int k = 0; k < BK; k++) {
            float a0 = As[ty * 4 + 0][k];
            float a1 = As[ty * 4 + 1][k];
            float a2 = As[ty * 4 + 2][k];
            float a3 = As[ty * 4 + 3][k];
            float4 b4 = *(const float4*)&Bs[k][tx * 4];
            acc[0][0] += a0 * b4.x; acc[0][1] += a0 * b4.y; acc[0][2] += a0 * b4.z; acc[0][3] += a0 * b4.w;
            acc[1][0] += a1 * b4.x; acc[1][1] += a1 * b4.y; acc[1][2] += a1 * b4.z; acc[1][3] += a1 * b4.w;
            acc[2][0] += a2 * b4.x; acc[2][1] += a2 * b4.y; acc[2][2] += a2 * b4.z; acc[2][3] += a2 * b4.w;
            acc[3][0] += a3 * b4.x; acc[3][1] += a3 * b4.y; acc[3][2] += a3 * b4.z; acc[3][3] += a3 * b4.w;
        }
        __syncthreads();
    }

#pragma unroll
    for (int i = 0; i < 4; i++) {
        int r = rowBase + ty * 4 + i;
#pragma unroll
        for (int jj = 0; jj < 4; jj++) {
            int col = colBase + tx * 4 + jj;
            if (col < G4) {
                int u = col % UU, g = col / UU;
                int p = 4 * u + g;
                out[(size_t)r * G4 + p] = f2bf(acc[i][jj] + ldf(bias, col, f32m));
            }
        }
    }
}

// ---------------------------------------------------------------------------
// Kernel 3: batched MFMA recurrence.  grid = 20 blocks (10 per dir), 256 thr.
// ---------------------------------------------------------------------------
__global__ __launch_bounds__(256) void lstm_rec2(
    const bf16_t* __restrict__ zxf, const bf16_t* __restrict__ zxb,
    const bf16_t* __restrict__ WrPT_f, const bf16_t* __restrict__ WrPT_b,
    const int* __restrict__ seqlen,
    bf16_t* __restrict__ Hglob, int* __restrict__ flags,
    bf16_t* __restrict__ hf, bf16_t* __restrict__ hb) {

    const int blk = blockIdx.x % KB;
    const int dir = blockIdx.x / KB;
    const bf16_t* zx   = dir ? zxb    : zxf;
    const bf16_t* WrPT = dir ? WrPT_b : WrPT_f;
    bf16_t*       hout = dir ? hb : hf;
    bf16_t*       Hg   = Hglob + (size_t)dir * (2 * BB * HROW);
    int*          fbase = flags + dir * (TT * 16);

    __shared__ __align__(16) uint16_t Wlds[NPAD * HSTR];  // 81,920 B
    __shared__ __align__(16) uint16_t Hlds[BB * HSTR];    // 20,480 B
    __shared__ __align__(16) float    zlds[BB * ZSTR];    // 16,896 B
    __shared__ float    clds[BB * UPB];                   //  3,840 B
    __shared__ uint16_t hstage[BB * UPB];                 //  1,920 B
    __shared__ int      sL[BB];

    const int tid = threadIdx.x;

    // one-time init: zero Wlds+Hlds (K-pad groups 38,39 and cols 120..127
    // must read as 0 in MFMA), then fill weights swizzled.
    for (int i = tid; i < NPAD * HSTR; i += 256) Wlds[i] = 0;
    for (int i = tid; i < BB * HSTR; i += 256) Hlds[i] = 0;
    __syncthreads();
    for (int i = tid; i < NCOL * 38; i += 256) {          // 38 groups of 8/col
        int c = i / 38, g = i - c * 38;
        *(uint4*)&Wlds[c * HSTR + (((g ^ (c & 7)) << 3))] =
            *(const uint4*)&WrPT[(size_t)(NCOL * blk + c) * HROW + g * 8];
    }
    for (int i = tid; i < BB * UPB; i += 256) clds[i] = 0.f;
    if (tid < BB) sL[tid] = seqlen[tid];
    __syncthreads();

    const int lane = tid & 63;
    const int wv   = tid >> 6;       // wave id 0..3 -> owns cols [32wv,32wv+32)
    const int q    = lane >> 4;      // quad 0..3
    const int c16  = lane & 15;
    const int n0   = 32 * wv;
    const int sw7  = c16 & 7;        // row&7 for all our fragment rows/cols
    const bool pollme = (lane < KB) && (lane != blk);

    for (int ts = 0; ts < TT; ts++) {
        const int t = dir ? (TT - 1 - ts) : ts;

        // zx prefetch FIRST — block-private, overlaps the flag wait
        uint2 zpre[4];
#pragma unroll
        for (int it = 0; it < 4; it++) {
            int w = tid + 256 * it;
            if (w < BB * UPB) {
                int b = w / UPB, ul = w - b * UPB;
                zpre[it] = *(const uint2*)&zx[((size_t)(b * TT + t)) * G4 +
                                              NCOL * blk + 4 * ul];
            }
        }

        if (ts > 0) {
            // wave-parallel flag poll: lanes 0..9 each watch one producer
            int* fl = fbase + (ts - 1) * 16;
            for (;;) {
                int v = pollme ? __hip_atomic_load(&fl[lane], __ATOMIC_RELAXED,
                                                   __HIP_MEMORY_SCOPE_AGENT)
                               : 1;
                if (__all(v != 0)) break;
                __builtin_amdgcn_s_sleep(1);
            }
        }

        // pipelined H reload: 2432 u64, 9..10 per thread, one vmcnt window
        const unsigned long long* Hsrc64 =
            (const unsigned long long*)(Hg + (size_t)(ts & 1) * (BB * HROW));
        unsigned long long hv[10];
#pragma unroll
        for (int k = 0; k < 9; k++)
            hv[k] = __hip_atomic_load(&Hsrc64[tid + 256 * k], __ATOMIC_RELAXED,
                                      __HIP_MEMORY_SCOPE_AGENT);
        if (tid < 128)
            hv[9] = __hip_atomic_load(&Hsrc64[2304 + tid], __ATOMIC_RELAXED,
                                      __HIP_MEMORY_SCOPE_AGENT);
#pragma unroll
        for (int k = 0; k < 9; k++) {
            int i = tid + 256 * k;
            int b = i / 76, x = i - 76 * b;
            *(unsigned long long*)
                &Hlds[b * HSTR + ((((x >> 1) ^ (b & 7)) << 3) | ((x & 1) << 2))]
                = hv[k];
        }
        if (tid < 128) {
            int i = 2304 + tid;
            int b = i / 76, x = i - 76 * b;
            *(unsigned long long*)
                &Hlds[b * HSTR + ((((x >> 1) ^ (b & 7)) << 3) | ((x & 1) << 2))]
                = hv[9];
        }
        __syncthreads();

        // z = H @ Wr_slice via MFMA (M=32, N=128, K=320), swizzled reads
        f32x4 acc00 = {0.f,0.f,0.f,0.f}, acc01 = {0.f,0.f,0.f,0.f};
        f32x4 acc10 = {0.f,0.f,0.f,0.f}, acc11 = {0.f,0.f,0.f,0.f};
#pragma unroll
        for (int kt = 0; kt < KTILES; kt++) {
            int sw = (((kt * 4 + q) ^ sw7) << 3);
            s16x8 a0 = *(const s16x8*)&Hlds[c16 * HSTR + sw];
            s16x8 a1 = *(const s16x8*)&Hlds[(c16 + 16) * HSTR + sw];
            s16x8 b0 = *(const s16x8*)&Wlds[(n0 + c16) * HSTR + sw];
            s16x8 b1 = *(const s16x8*)&Wlds[(n0 + 16 + c16) * HSTR + sw];
            acc00 = __builtin_amdgcn_mfma_f32_16x16x32_bf16(a0, b0, acc00, 0, 0, 0);
            acc01 = __builtin_amdgcn_mfma_f32_16x16x32_bf16(a0, b1, acc01, 0, 0, 0);
            acc10 = __builtin_amdgcn_mfma_f32_16x16x32_bf16(a1, b0, acc10, 0, 0, 0);
            acc11 = __builtin_amdgcn_mfma_f32_16x16x32_bf16(a1, b1, acc11, 0, 0, 0);
        }
#pragma unroll
        for (int r = 0; r < 4; r++) {
            int row = 4 * q + r;
            zlds[row * ZSTR + n0 + c16]             = acc00[r];
            zlds[row * ZSTR + n0 + 16 + c16]        = acc01[r];
            zlds[(16 + row) * ZSTR + n0 + c16]      = acc10[r];
            zlds[(16 + row) * ZSTR + n0 + 16 + c16] = acc11[r];
        }
        __syncthreads();

        // gates + state update for 32 batches x our 30 units
#pragma unroll
        for (int it = 0; it < 4; it++) {
            int w = tid + 256 * it;
            if (w < BB * UPB) {
                int b = w / UPB, ul = w - b * UPB;
                float4 z4 = *(const float4*)&zlds[b * ZSTR + 4 * ul];
                uint2 zp = zpre[it];
                float zi = z4.x + bf2f((uint16_t)(zp.x & 0xffff));
                float zf = z4.y + bf2f((uint16_t)(zp.x >> 16));
                float zg = z4.z + bf2f((uint16_t)(zp.y & 0xffff));
                float zo = z4.w + bf2f((uint16_t)(zp.y >> 16));
                float si = 1.f / (1.f + __expf(-zi));
                float sf = 1.f / (1.f + __expf(-zf));
                float so = 1.f / (1.f + __expf(-zo));
                float tg = tanhf(zg);
                float cold = clds[w];
                float cn = sf * cold + si * tg;
                float hn = so * tanhf(cn);
                bool m = (t < sL[b]);
                int e = UPB * blk + ul;
                float hold = bf2f(Hlds[swz(b, e)]);
                float hw = m ? hn : hold;
                clds[w] = m ? cn : cold;
                bf16_t h16 = f2bf(hw);
                hstage[w] = h16;
                hout[((size_t)(b * TT + t)) * UU + e] = h16;   // private store
            }
        }
        __syncthreads();

        if (ts < TT - 1) {
            // publish our H columns: paired u32 write-through atomic stores
            bf16_t* Hdst = Hg + (size_t)((ts + 1) & 1) * (BB * HROW);
            for (int i = tid; i < BB * (UPB / 2); i += 256) { // 480 pairs
                int b = i / (UPB / 2), k = i - b * (UPB / 2);
                uint32_t val = (uint32_t)hstage[b * UPB + 2 * k] |
                               ((uint32_t)hstage[b * UPB + 2 * k + 1] << 16);
                __hip_atomic_store(
                    (uint32_t*)&Hdst[b * HROW + UPB * blk + 2 * k], val,
                    __ATOMIC_RELAXED, __HIP_MEMORY_SCOPE_AGENT);
            }
            // syncthreads drains every wave's vmcnt (stores acked at L3),
            // then one flag STORE (no RMW -> no serialization).
            __syncthreads();
            if (tid == 0)
                __hip_atomic_store(&fbase[ts * 16 + blk], 1, __ATOMIC_RELAXED,
                                   __HIP_MEMORY_SCOPE_AGENT);
        }
    }
}

// ---------------------------------------------------------------------------
// Kernel 4: out[r] = [hf[r] ; hb[r]] @ fc_W + fc_b.
// ---------------------------------------------------------------------------
__global__ __launch_bounds__(256) void fc_out(
    const bf16_t* __restrict__ hf, const bf16_t* __restrict__ hb,
    const void* __restrict__ fcW, const void* __restrict__ fcb,
    void* __restrict__ out, const int* __restrict__ flagp) {

    const int f32m = *flagp;
    __shared__ float W[2 * UU * NTOK];
    __shared__ float bias[NTOK];
    const int tid = threadIdx.x;
    for (int i = tid; i < 2 * UU * NTOK; i += 256) W[i] = ldf(fcW, i, f32m);
    if (tid < NTOK) bias[tid] = ldf(fcb, tid, f32m);
    __syncthreads();

    const int r = blockIdx.x * 256 + tid;
    const bf16_t* hfr = hf + (size_t)r * UU;
    const bf16_t* hbr = hb + (size_t)r * UU;
    float s0 = bias[0], s1 = bias[1], s2 = bias[2];
    for (int u = 0; u < UU; u++) {
        float f = bf2f(hfr[u]);
        s0 += f * W[u * 3 + 0];
        s1 += f * W[u * 3 + 1];
        s2 += f * W[u * 3 + 2];
    }
    for (int u = 0; u < UU; u++) {
        float f = bf2f(hbr[u]);
        s0 += f * W[(UU + u) * 3 + 0];
        s1 += f * W[(UU + u) * 3 + 1];
        s2 += f * W[(UU + u) * 3 + 2];
    }
    if (f32m) {
        float* o = (float*)out;
        o[(size_t)r * 3 + 0] = s0;
        o[(size_t)r * 3 + 1] = s1;
        o[(size_t)r * 3 + 2] = s2;
    } else {
        bf16_t* o = (bf16_t*)out;
        o[(size_t)r * 3 + 0] = f2bf(s0);
        o[(size_t)r * 3 + 1] = f2bf(s1);
        o[(size_t)r * 3 + 2] = f2bf(s2);
    }
}

// ---------------------------------------------------------------------------
extern "C" void kernel_launch(void* const* d_in, const int* in_sizes, int n_in,
                              void* d_out, int out_size, void* d_ws, size_t ws_size,
                              hipStream_t stream) {
    const int* inputs = (const int*)d_in[0];
    const int* seqlen = (const int*)d_in[1];
    const void* emb  = d_in[2];
    const void* Wk_f = d_in[3];
    const void* Wr_f = d_in[4];
    const void* b_f  = d_in[5];
    const void* Wk_b = d_in[6];
    const void* Wr_b = d_in[7];
    const void* b_b  = d_in[8];
    const void* fcW  = d_in[9];
    const void* fcb  = d_in[10];

    // workspace layout (bytes), 16B aligned
    char* ws = (char*)d_ws;
    int*    flag   = (int*)(ws + 0);                 // 64 B
    int*    flags  = (int*)(ws + 64);                // 2*512*16*4 = 65,536
    bf16_t* Hglob  = (bf16_t*)(ws + 65664);          // 2*2*32*304*2 = 77,824
    bf16_t* WrPT_f = (bf16_t*)(ws + 143488);         // 729,600
    bf16_t* WrPT_b = (bf16_t*)(ws + 873088);         // 729,600
    bf16_t* zxPf   = (bf16_t*)(ws + 1602688);        // 39,321,600
    bf16_t* zxPb   = (bf16_t*)(ws + 40924288);       // 39,321,600
    bf16_t* hfbuf  = (bf16_t*)(ws + 80245888);       // 9,830,400
    bf16_t* hbbuf  = (bf16_t*)(ws + 90076288);       // 9,830,400 -> 99,906,688

    detect_dtype<<<1, 256, 0, stream>>>((const uint16_t*)emb, flag);
    {
        dim3 grid((G4 * HROW + 255) / 256, 2);
        prep_wrp<<<grid, 256, 0, stream>>>(Wr_f, Wr_b, WrPT_f, WrPT_b, flag);
    }
    init_state<<<160, 256, 0, stream>>>(Hglob, flags);
    {
        dim3 grid((G4 + BN - 1) / BN, (BB * TT) / BM, 2);
        zx_gemm<<<grid, 256, 0, stream>>>(inputs, emb, Wk_f, b_f, Wk_b, b_b,
                                          zxPf, zxPb, flag);
    }
    lstm_rec2<<<2 * KB, 256, 0, stream>>>(zxPf, zxPb, WrPT_f, WrPT_b, seqlen,
                                          Hglob, flags, hfbuf, hbbuf);
    fc_out<<<(BB * TT) / 256, 256, 0, stream>>>(hfbuf, hbbuf, fcW, fcb,
                                                d_out, flag);
}